// Round 4
// baseline (265.367 us; speedup 1.0000x reference)
//
#include <hip/hip_runtime.h>
#include <hip/hip_bf16.h>

// Flash-attention prefill w/ GQA, causal + sliding-window(1024), attention sink.
// B=1, S=2048, Hq=32, Hkv=8, D=128. fp32 in/out; bf16 MFMA compute, fp32 accum.
// R10: barrier-free direct-from-L2 fragment streaming.
//   Post-mortems: R8 (halved LDS reads, lost TLP) and R9 (halved L2 traffic,
//   flat) => L2 has slack, LDS pipe + barrier lockstep are the binders.
//   New: NO staging, NO barriers. Each wave = 32 q-rows x 1 head (R8's proven
//   2-i-frag fragment math), reads K/V MFMA fragments DIRECTLY from packed
//   kp/vtp (L2-resident, XCD-local) via global_load_dwordx4 using the same
//   pc/qp swizzled offsets. K frags double-buffered in registers across
//   iterations; V frags loaded at iter top, used ~500cy later. Only LDS use:
//   per-wave P roundtrip (same-wave lgkmcnt, no sync). Blocks = 4 independent
//   waves, row-groups {u,31-u,32+u,63-u} -> every block = exactly 99 tiles.
//   512 blocks x 256 thr, 2 blocks/CU, VGPR~230 (2 waves/SIMD, never parked).

#define S_LEN 2048
#define DH    128
#define HQ    32
#define HKV   8
#define WIN   1024
#define BC    32
#define NT    (S_LEN / BC)          // 64 j-tiles
#define FM    16.0f                 // fixed log2-domain softmax max
#define TILE_CH 512                 // 16B chunks per 32x128 bf16 tile

typedef unsigned short u16;
typedef __attribute__((ext_vector_type(8))) short  short8;
typedef __attribute__((ext_vector_type(4))) float  floatx4;
typedef __attribute__((ext_vector_type(4))) unsigned int uintx4;

__device__ __forceinline__ unsigned rne1(float a) {
    unsigned u = __float_as_uint(a);
    return (u + 0x7FFFu + ((u >> 16) & 1u)) >> 16;
}
__device__ __forceinline__ unsigned rne_pk(float a, float b) {
    return rne1(a) | (rne1(b) << 16);
}
// single-instruction RNE pack (same rounding as rne_pk; validated R8/R9)
__device__ __forceinline__ unsigned cvt_pk(float a, float b) {
    unsigned r;
    asm("v_cvt_pk_bf16_f32 %0, %1, %2" : "=v"(r) : "v"(a), "v"(b));
    return r;
}

// ---------------- pre-pass: pack K/V^T to bf16 in ws (UNCHANGED) ----------------
__global__ __launch_bounds__(256) void pack_kv(const float* __restrict__ kg,
                                               const float* __restrict__ vg,
                                               u16* __restrict__ kp,
                                               u16* __restrict__ vtp)
{
    __shared__ float Vs[BC][DH + 1];
    const int b   = blockIdx.x;
    const int hk  = b >> 6;
    const int jt  = b & 63;
    const int tid = threadIdx.x;
    const int j0  = jt * BC;

    #pragma unroll
    for (int t = 0; t < 4; t++) {
        int idx = tid + t * 256;        // float4 id 0..1023
        int j   = idx >> 5;
        int dc  = idx & 31;
        floatx4 f = *(const floatx4*)(vg + ((size_t)(j0 + j) * HKV + hk) * DH + dc * 4);
        Vs[j][dc * 4 + 0] = f[0]; Vs[j][dc * 4 + 1] = f[1];
        Vs[j][dc * 4 + 2] = f[2]; Vs[j][dc * 4 + 3] = f[3];
    }

    u16* kpt = kp + (size_t)b * TILE_CH * 8;
    #pragma unroll
    for (int t = 0; t < 2; t++) {
        int c = tid + t * 256;
        int row = c >> 4, cc = c & 15;
        const float* p = kg + ((size_t)(j0 + row) * HKV + hk) * DH + cc * 8;
        floatx4 f0 = *(const floatx4*)p;
        floatx4 f1 = *(const floatx4*)(p + 4);
        int pc = (row << 4) | (cc ^ (row & 7));
        *(uintx4*)(kpt + pc * 8) =
            (uintx4){rne_pk(f0[0], f0[1]), rne_pk(f0[2], f0[3]),
                     rne_pk(f1[0], f1[1]), rne_pk(f1[2], f1[3])};
    }
    __syncthreads();

    u16* vpt = vtp + (size_t)b * TILE_CH * 8;
    #pragma unroll
    for (int t = 0; t < 2; t++) {
        int q  = tid + t * 256;
        int dd = q >> 2, c = q & 3;
        unsigned w0 = rne_pk(Vs[c * 4 + 0][dd], Vs[c * 4 + 16][dd]);
        unsigned w1 = rne_pk(Vs[c * 4 + 1][dd], Vs[c * 4 + 17][dd]);
        unsigned w2 = rne_pk(Vs[c * 4 + 2][dd], Vs[c * 4 + 18][dd]);
        unsigned w3 = rne_pk(Vs[c * 4 + 3][dd], Vs[c * 4 + 19][dd]);
        int qp = (dd << 2) | (c ^ ((dd >> 2) & 3));
        *(uintx4*)(vpt + qp * 8) = (uintx4){w0, w1, w2, w3};
    }
}

// -------- main flash kernel (R10: barrier-free, direct-from-L2 fragments) --------
__launch_bounds__(256, 2)
__global__ void fa_kernel(const float* __restrict__ qg,
                          const u16* __restrict__ kp,
                          const u16* __restrict__ vtp,
                          const float* __restrict__ sg,
                          float* __restrict__ outg)
{
    __shared__ __align__(16) u16 Pb[4 * 32 * 40];     // 10 KB, per-wave slices

    const int tid  = threadIdx.x;
    const int w    = tid >> 6;          // wave 0..3 (fully independent)
    const int lane = tid & 63;
    const int quad = lane >> 4;
    const int l16  = lane & 15;

    // Mapping: hk = bid&7 (XCD-local KV). idx -> (head, u). Waves take the
    // row-group quad {u, 31-u, 32+u, 63-u}: per-block total = exactly 99 tiles.
    const int bid  = blockIdx.x;
    const int hk   = bid & 7;
    const int idx  = bid >> 3;          // 0..63
    const int hrem = idx & 3;
    const int u    = idx >> 2;          // 0..15
    const int h    = hk * 4 + hrem;
    const int rgt[4] = {u, 31 - u, 32 + u, 63 - u};
    const int rg   = rgt[w];
    const int i0w  = rg * 32;           // this wave's 32 q-rows

    // ---- Q A-fragments: 2 row-frags x 4 k-chunks (once) ----
    short8 qf[2][4];
    #pragma unroll
    for (int m = 0; m < 2; m++) {
        const float* qrow = qg + ((size_t)(i0w + m * 16 + l16) * HQ + h) * DH;
        #pragma unroll
        for (int kk = 0; kk < 4; kk++) {
            const float* p = qrow + kk * 32 + quad * 8;
            floatx4 f0 = *(const floatx4*)p;
            floatx4 f1 = *(const floatx4*)(p + 4);
            uintx4 uq = (uintx4){cvt_pk(f0[0], f0[1]), cvt_pk(f0[2], f0[3]),
                                 cvt_pk(f1[0], f1[1]), cvt_pk(f1[2], f1[3])};
            qf[m][kk] = *(short8*)&uq;
        }
    }

    // ---- per-lane fragment element offsets within an 8 KB tile ----
    int koff[8], voff[8];
    #pragma unroll
    for (int n = 0; n < 2; n++)
        #pragma unroll
        for (int kk = 0; kk < 4; kk++) {
            int row = n * 16 + l16;
            int cc  = kk * 4 + quad;
            koff[n * 4 + kk] = ((row << 4) | (cc ^ (row & 7))) * 8;
        }
    #pragma unroll
    for (int nf = 0; nf < 8; nf++) {
        int dd = nf * 16 + l16;
        voff[nf] = ((dd << 2) | (quad ^ ((dd >> 2) & 3))) * 8;
    }

    floatx4 acc[2][8];
    #pragma unroll
    for (int m = 0; m < 2; m++)
        #pragma unroll
        for (int i = 0; i < 8; i++) acc[m][i] = (floatx4){0.f, 0.f, 0.f, 0.f};
    float l_part[2][4] = {{0.f, 0.f, 0.f, 0.f}, {0.f, 0.f, 0.f, 0.f}};

    int c_r[2][4];
    #pragma unroll
    for (int m = 0; m < 2; m++)
        #pragma unroll
        for (int r = 0; r < 4; r++)
            c_r[m][r] = i0w + m * 16 + quad * 4 + r - l16;   // i_g - l16

    int jlo = i0w - (WIN - 1); if (jlo < 0) jlo = 0;
    const int jt_lo = jlo >> 5;
    const int jt_hi = rg;               // (i0w+31)>>5 == rg

    const float SC2 = 0.08838834764831845f * 1.4426950408889634f;

    const u16* kbase = kp  + (((size_t)hk * NT) << 12);   // tile stride 4096 u16
    const u16* vbase = vtp + (((size_t)hk * NT) << 12);

    short8 kfA[8], kfB[8], vf[8];

    auto loadK = [&](short8 (&kf)[8], int jtt) {
        const u16* t = kbase + ((size_t)jtt << 12);
        #pragma unroll
        for (int i = 0; i < 8; i++) kf[i] = *(const short8*)(t + koff[i]);
    };
    auto loadV = [&](int jtt) {
        const u16* t = vbase + ((size_t)jtt << 12);
        #pragma unroll
        for (int i = 0; i < 8; i++) vf[i] = *(const short8*)(t + voff[i]);
    };

    auto compute = [&](int j0, short8 (&kf)[8]) {
        // ---- QK^T: 16 mfma, kf shared across the 2 row-frags ----
        floatx4 sc[2][2];
        #pragma unroll
        for (int m = 0; m < 2; m++) {
            sc[m][0] = (floatx4){0.f, 0.f, 0.f, 0.f};
            sc[m][1] = (floatx4){0.f, 0.f, 0.f, 0.f};
        }
        __builtin_amdgcn_s_setprio(1);
        #pragma unroll
        for (int kk = 0; kk < 4; kk++) {
            sc[0][0] = __builtin_amdgcn_mfma_f32_16x16x32_bf16(qf[0][kk], kf[kk],     sc[0][0], 0, 0, 0);
            sc[1][0] = __builtin_amdgcn_mfma_f32_16x16x32_bf16(qf[1][kk], kf[kk],     sc[1][0], 0, 0, 0);
            sc[0][1] = __builtin_amdgcn_mfma_f32_16x16x32_bf16(qf[0][kk], kf[4 + kk], sc[0][1], 0, 0, 0);
            sc[1][1] = __builtin_amdgcn_mfma_f32_16x16x32_bf16(qf[1][kk], kf[4 + kk], sc[1][1], 0, 0, 0);
        }
        __builtin_amdgcn_s_setprio(0);

        // ---- softmax: fixed max, pair-interleaved P (col j | col j+16) ----
        const bool interior = (j0 + (BC - 1) <= i0w) && (j0 >= i0w + 32 - WIN);
        if (interior) {
            #pragma unroll
            for (int m = 0; m < 2; m++) {
                const int prow0 = w * 32 + m * 16 + quad * 4;
                #pragma unroll
                for (int r = 0; r < 4; r++) {
                    float p0 = exp2f(fmaf(sc[m][0][r], SC2, -FM));
                    float p1 = exp2f(fmaf(sc[m][1][r], SC2, -FM));
                    l_part[m][r] += p0 + p1;
                    *(unsigned*)(&Pb[(prow0 + r) * 40 + l16 * 2]) = cvt_pk(p0, p1);
                }
            }
        } else {
            #pragma unroll
            for (int m = 0; m < 2; m++) {
                const int prow0 = w * 32 + m * 16 + quad * 4;
                #pragma unroll
                for (int r = 0; r < 4; r++) {
                    bool a0 = (j0 <= c_r[m][r]) && (j0 > c_r[m][r] - WIN);
                    bool a1 = (j0 + 16 <= c_r[m][r]) && (j0 + 16 > c_r[m][r] - WIN);
                    float p0 = a0 ? exp2f(fmaf(sc[m][0][r], SC2, -FM)) : 0.f;
                    float p1 = a1 ? exp2f(fmaf(sc[m][1][r], SC2, -FM)) : 0.f;
                    l_part[m][r] += p0 + p1;
                    *(unsigned*)(&Pb[(prow0 + r) * 40 + l16 * 2]) = cvt_pk(p0, p1);
                }
            }
        }

        // ---- PV: 16 mfma (P via same-wave LDS roundtrip, lgkmcnt only) ----
        short8 pf0 = *(const short8*)(&Pb[(w * 32 + l16) * 40 + quad * 8]);
        short8 pf1 = *(const short8*)(&Pb[(w * 32 + 16 + l16) * 40 + quad * 8]);
        __builtin_amdgcn_s_setprio(1);
        #pragma unroll
        for (int nf = 0; nf < 8; nf++) {
            acc[0][nf] = __builtin_amdgcn_mfma_f32_16x16x32_bf16(pf0, vf[nf], acc[0][nf], 0, 0, 0);
            acc[1][nf] = __builtin_amdgcn_mfma_f32_16x16x32_bf16(pf1, vf[nf], acc[1][nf], 0, 0, 0);
        }
        __builtin_amdgcn_s_setprio(0);
    };

    // ---- main loop: unroll-2 register double-buffer for K, V within-iter ----
    int jt = jt_lo;
    loadK(kfA, jt);
    for (;;) {
        loadV(jt);
        if (jt < jt_hi) loadK(kfB, jt + 1);
        compute(jt << 5, kfA);
        if (++jt > jt_hi) break;

        loadV(jt);
        if (jt < jt_hi) loadK(kfA, jt + 1);
        compute(jt << 5, kfB);
        if (++jt > jt_hi) break;
    }

    // ---- epilogue ----
    const float sk2 = exp2f(fmaf(sg[h], 1.4426950408889634f, -FM));
    float inv[2][4];
    #pragma unroll
    for (int m = 0; m < 2; m++)
        #pragma unroll
        for (int r = 0; r < 4; r++) {
            float l = l_part[m][r];
            #pragma unroll
            for (int off = 1; off < 16; off <<= 1)
                l += __shfl_xor(l, off);
            inv[m][r] = 1.f / (l + sk2);
        }
    #pragma unroll
    for (int m = 0; m < 2; m++)
        #pragma unroll
        for (int nf = 0; nf < 8; nf++) {
            int d = nf * 16 + l16;
            #pragma unroll
            for (int r = 0; r < 4; r++) {
                int ig = i0w + m * 16 + quad * 4 + r;
                outg[((size_t)ig * HQ + h) * DH + d] = acc[m][nf][r] * inv[m][r];
            }
        }
}

// ---------------- fallback (used only if ws too small; UNCHANGED) ----------------
__launch_bounds__(256, 4)
__global__ void fa_fallback(const float* __restrict__ qg,
                            const float* __restrict__ kg,
                            const float* __restrict__ vg,
                            const float* __restrict__ sg,
                            float* __restrict__ outg)
{
    __shared__ __align__(16) u16 Kt[BC * DH];
    __shared__ __align__(16) u16 Vt[DH * BC];
    __shared__ __align__(16) u16 Pb[64 * 40];

    const int tid  = threadIdx.x;
    const int w    = tid >> 6;
    const int lane = tid & 63;
    const int quad = lane >> 4;
    const int l16  = lane & 15;

    const int qb = blockIdx.x / HQ;
    const int h  = blockIdx.x % HQ;
    const int hk = h >> 2;
    const int i0 = qb * 64;
    const int m0 = i0 + w * 16;

    short8 qf[4];
    {
        const float* qrow = qg + ((size_t)(m0 + l16) * HQ + h) * DH;
        #pragma unroll
        for (int kk = 0; kk < 4; kk++) {
            const float* p = qrow + kk * 32 + quad * 8;
            floatx4 f0 = *(const floatx4*)p;
            floatx4 f1 = *(const floatx4*)(p + 4);
            uintx4 u = (uintx4){rne_pk(f0[0], f0[1]), rne_pk(f0[2], f0[3]),
                                rne_pk(f1[0], f1[1]), rne_pk(f1[2], f1[3])};
            qf[kk] = *(short8*)&u;
        }
    }

    floatx4 acc[8];
    #pragma unroll
    for (int i = 0; i < 8; i++) acc[i] = (floatx4){0.f, 0.f, 0.f, 0.f};
    float l_part[4] = {0.f, 0.f, 0.f, 0.f};

    int jlo = i0 - (WIN - 1); if (jlo < 0) jlo = 0;
    const int jt_lo = jlo >> 5;
    const int jt_hi = (i0 + 63) >> 5;
    const float SC2 = 0.08838834764831845f * 1.4426950408889634f;

    for (int jt = jt_lo; jt <= jt_hi; jt++) {
        const int j0 = jt << 5;
        __syncthreads();
        #pragma unroll
        for (int it = 0; it < 2; it++) {
            int g   = tid + 256 * it;
            int row = g >> 4, cc = g & 15;
            int pc  = (row << 4) | (cc ^ (row & 7));
            const float* kpp = kg + ((size_t)(j0 + row) * HKV + hk) * DH + cc * 8;
            floatx4 f0 = *(const floatx4*)kpp;
            floatx4 f1 = *(const floatx4*)(kpp + 4);
            *(uintx4*)(&Kt[pc * 8]) =
                (uintx4){rne_pk(f0[0], f0[1]), rne_pk(f0[2], f0[3]),
                         rne_pk(f1[0], f1[1]), rne_pk(f1[2], f1[3])};
        }
        #pragma unroll
        for (int it = 0; it < 2; it++) {
            int g  = tid + 256 * it;
            int d  = g & 127, jc = g >> 7;
            const float* vp = vg + ((size_t)(j0 + jc * 8) * HKV + hk) * DH + d;
            float e0 = vp[0 * HKV * DH], e1 = vp[1 * HKV * DH];
            float e2 = vp[2 * HKV * DH], e3 = vp[3 * HKV * DH];
            float e4 = vp[4 * HKV * DH], e5 = vp[5 * HKV * DH];
            float e6 = vp[6 * HKV * DH], e7 = vp[7 * HKV * DH];
            int pc = (d << 2) | (jc ^ ((d >> 2) & 3));
            *(uintx4*)(&Vt[pc * 8]) =
                (uintx4){rne_pk(e0, e1), rne_pk(e2, e3), rne_pk(e4, e5), rne_pk(e6, e7)};
        }
        __syncthreads();

        floatx4 sc[2];
        sc[0] = (floatx4){0.f, 0.f, 0.f, 0.f};
        sc[1] = (floatx4){0.f, 0.f, 0.f, 0.f};
        #pragma unroll
        for (int kk = 0; kk < 4; kk++) {
            #pragma unroll
            for (int n = 0; n < 2; n++) {
                int row = n * 16 + l16;
                int cc  = kk * 4 + quad;
                int pc  = (row << 4) | (cc ^ (row & 7));
                short8 kf = *(const short8*)(&Kt[pc * 8]);
                sc[n] = __builtin_amdgcn_mfma_f32_16x16x32_bf16(qf[kk], kf, sc[n], 0, 0, 0);
            }
        }
        #pragma unroll
        for (int r = 0; r < 4; r++) {
            int   i_g = m0 + quad * 4 + r;
            int   jg0 = j0 + l16, jg1 = j0 + 16 + l16;
            bool  a0  = (jg0 <= i_g) && (i_g - jg0 < WIN);
            bool  a1  = (jg1 <= i_g) && (i_g - jg1 < WIN);
            float p0  = a0 ? exp2f(fmaf(sc[0][r], SC2, -FM)) : 0.f;
            float p1  = a1 ? exp2f(fmaf(sc[1][r], SC2, -FM)) : 0.f;
            l_part[r] += p0 + p1;
            int prow = w * 16 + quad * 4 + r;
            *(unsigned*)(&Pb[prow * 40 + 2 * l16]) = rne_pk(p0, p1);
        }
        {
            short8 pf = *(const short8*)(&Pb[(w * 16 + l16) * 40 + quad * 8]);
            #pragma unroll
            for (int nf = 0; nf < 8; nf++) {
                int dd = nf * 16 + l16;
                int qp = (dd << 2) | (quad ^ ((dd >> 2) & 3));
                short8 vf = *(const short8*)(&Vt[qp * 8]);
                acc[nf] = __builtin_amdgcn_mfma_f32_16x16x32_bf16(pf, vf, acc[nf], 0, 0, 0);
            }
        }
    }

    const float sk2 = exp2f(fmaf(sg[h], 1.4426950408889634f, -FM));
    float inv[4];
    #pragma unroll
    for (int r = 0; r < 4; r++) {
        float l = l_part[r];
        #pragma unroll
        for (int off = 1; off < 16; off <<= 1)
            l += __shfl_xor(l, off);
        inv[r] = 1.f / (l + sk2);
    }
    #pragma unroll
    for (int nf = 0; nf < 8; nf++) {
        int d = nf * 16 + l16;
        #pragma unroll
        for (int r = 0; r < 4; r++) {
            int ig = m0 + quad * 4 + r;
            outg[((size_t)ig * HQ + h) * DH + d] = acc[nf][r] * inv[r];
        }
    }
}

extern "C" void kernel_launch(void* const* d_in, const int* in_sizes, int n_in,
                              void* d_out, int out_size, void* d_ws, size_t ws_size,
                              hipStream_t stream) {
    const float* q  = (const float*)d_in[0];
    const float* k  = (const float*)d_in[1];
    const float* v  = (const float*)d_in[2];
    const float* sk = (const float*)d_in[3];
    float* out = (float*)d_out;

    const size_t tile_elems = (size_t)HKV * NT * TILE_CH * 8;   // u16 elems per tensor
    const size_t need = 2 * tile_elems * sizeof(u16);           // 8 MB

    if (ws_size >= need) {
        u16* kp  = (u16*)d_ws;
        u16* vtp = kp + tile_elems;
        pack_kv<<<dim3(HKV * NT), 256, 0, stream>>>(k, v, kp, vtp);
        // 512 blocks x 256 thr: 8 hk x 4 hrem x 16 u; waves take rg quad
        // {u, 31-u, 32+u, 63-u} -> every block exactly 99 j-tiles.
        fa_kernel<<<dim3(512), 256, 0, stream>>>(q, kp, vtp, sk, out);
    } else {
        fa_fallback<<<dim3((S_LEN / 64) * HQ), 256, 0, stream>>>(q, k, v, sk, out);
    }
}

// Round 5
// 174.522 us; speedup vs baseline: 1.5205x; 1.5205x over previous
//
#include <hip/hip_runtime.h>
#include <hip/hip_bf16.h>

// Flash-attention prefill w/ GQA, causal + sliding-window(1024), attention sink.
// B=1, S=2048, Hq=32, Hkv=8, D=128. fp32 in/out; bf16 MFMA compute, fp32 accum.
// R11: champion R4/R6 structure (256 thr, 4 waves x 16 rows, 1024 blocks,
// XCD-local hk=bid&7, balanced qb quad, K double-buffered via global_load_lds,
// one barrier/iter, fixed-max softmax) with ONE structural change:
//   V fragments are read DIRECTLY from the packed L2-resident vtp (global),
//   not staged through LDS. The voff pattern is fully coalesced (each vf load
//   = one contiguous 1KB span per wave). Removes 8/17 per-wave LDS reads and
//   half the staging DMA; R9 proved L2 has >=2x slack. VGPR ~100 < 128 cap
//   (R10's spill lesson: keep live state small). cvt_pk kept (validated).

#define S_LEN 2048
#define DH    128
#define HQ    32
#define HKV   8
#define WIN   1024
#define BR    64
#define BC    32
#define NT    (S_LEN / BC)          // 64 j-tiles
#define FM    16.0f                 // fixed log2-domain softmax max
#define TILE_CH 512                 // 16B chunks per 32x128 bf16 tile

typedef unsigned short u16;
typedef __attribute__((ext_vector_type(8))) short  short8;
typedef __attribute__((ext_vector_type(4))) float  floatx4;
typedef __attribute__((ext_vector_type(4))) unsigned int uintx4;

__device__ __forceinline__ unsigned rne1(float a) {
    unsigned u = __float_as_uint(a);
    return (u + 0x7FFFu + ((u >> 16) & 1u)) >> 16;
}
__device__ __forceinline__ unsigned rne_pk(float a, float b) {
    return rne1(a) | (rne1(b) << 16);
}
// single-instruction RNE pack (same rounding as rne_pk; validated R8/R9)
__device__ __forceinline__ unsigned cvt_pk(float a, float b) {
    unsigned r;
    asm("v_cvt_pk_bf16_f32 %0, %1, %2" : "=v"(r) : "v"(a), "v"(b));
    return r;
}

// ---------------- pre-pass: pack K/V^T to bf16 in ws (UNCHANGED) ----------------
__global__ __launch_bounds__(256) void pack_kv(const float* __restrict__ kg,
                                               const float* __restrict__ vg,
                                               u16* __restrict__ kp,
                                               u16* __restrict__ vtp)
{
    __shared__ float Vs[BC][DH + 1];
    const int b   = blockIdx.x;
    const int hk  = b >> 6;
    const int jt  = b & 63;
    const int tid = threadIdx.x;
    const int j0  = jt * BC;

    #pragma unroll
    for (int t = 0; t < 4; t++) {
        int idx = tid + t * 256;        // float4 id 0..1023
        int j   = idx >> 5;
        int dc  = idx & 31;
        floatx4 f = *(const floatx4*)(vg + ((size_t)(j0 + j) * HKV + hk) * DH + dc * 4);
        Vs[j][dc * 4 + 0] = f[0]; Vs[j][dc * 4 + 1] = f[1];
        Vs[j][dc * 4 + 2] = f[2]; Vs[j][dc * 4 + 3] = f[3];
    }

    u16* kpt = kp + (size_t)b * TILE_CH * 8;
    #pragma unroll
    for (int t = 0; t < 2; t++) {
        int c = tid + t * 256;
        int row = c >> 4, cc = c & 15;
        const float* p = kg + ((size_t)(j0 + row) * HKV + hk) * DH + cc * 8;
        floatx4 f0 = *(const floatx4*)p;
        floatx4 f1 = *(const floatx4*)(p + 4);
        int pc = (row << 4) | (cc ^ (row & 7));
        *(uintx4*)(kpt + pc * 8) =
            (uintx4){rne_pk(f0[0], f0[1]), rne_pk(f0[2], f0[3]),
                     rne_pk(f1[0], f1[1]), rne_pk(f1[2], f1[3])};
    }
    __syncthreads();

    u16* vpt = vtp + (size_t)b * TILE_CH * 8;
    #pragma unroll
    for (int t = 0; t < 2; t++) {
        int q  = tid + t * 256;
        int dd = q >> 2, c = q & 3;
        unsigned w0 = rne_pk(Vs[c * 4 + 0][dd], Vs[c * 4 + 16][dd]);
        unsigned w1 = rne_pk(Vs[c * 4 + 1][dd], Vs[c * 4 + 17][dd]);
        unsigned w2 = rne_pk(Vs[c * 4 + 2][dd], Vs[c * 4 + 18][dd]);
        unsigned w3 = rne_pk(Vs[c * 4 + 3][dd], Vs[c * 4 + 19][dd]);
        int qp = (dd << 2) | (c ^ ((dd >> 2) & 3));
        *(uintx4*)(vpt + qp * 8) = (uintx4){w0, w1, w2, w3};
    }
}

// -------- main flash kernel (R11: R4 structure, V direct from global) --------
__launch_bounds__(256, 4)
__global__ void fa_kernel(const float* __restrict__ qg,
                          const u16* __restrict__ kp,
                          const u16* __restrict__ vtp,
                          const float* __restrict__ sg,
                          float* __restrict__ outg)
{
    __shared__ __align__(16) u16 Kt[2][TILE_CH * 8];   // 2 x 8 KB (K only)
    __shared__ __align__(16) u16 Pb[BR * 40];          // 5 KB

    const int tid  = threadIdx.x;
    const int w    = tid >> 6;
    const int lane = tid & 63;
    const int quad = lane >> 4;
    const int l16  = lane & 15;

    // R6 mapping: hk = bid&7 (XCD-local KV); per-CU-slot qb set is balanced.
    const int bid  = blockIdx.x;
    const int hk   = bid & 7;
    const int idx  = bid >> 3;          // 0..127 within this hk
    const int hrem = idx & 3;
    const int u5   = (idx >> 2) & 7;
    const int t4   = idx >> 5;          // 0..3
    const int qbt[4] = {u5, 15 - u5, 16 + u5, 31 - u5};
    const int qb   = qbt[t4];
    const int h    = hk * 4 + hrem;

    const int i0 = qb * BR;
    const int m0 = i0 + w * 16;

    // ---- Q A-fragments (once per block) ----
    short8 qf[4];
    {
        const float* qrow = qg + ((size_t)(m0 + l16) * HQ + h) * DH;
        #pragma unroll
        for (int kk = 0; kk < 4; kk++) {
            const float* p = qrow + kk * 32 + quad * 8;
            floatx4 f0 = *(const floatx4*)p;
            floatx4 f1 = *(const floatx4*)(p + 4);
            uintx4 uq = (uintx4){cvt_pk(f0[0], f0[1]), cvt_pk(f0[2], f0[3]),
                                 cvt_pk(f1[0], f1[1]), cvt_pk(f1[2], f1[3])};
            qf[kk] = *(short8*)&uq;
        }
    }

    // ---- per-lane V fragment offsets (u16 units) within an 8 KB tile ----
    int voff[8];
    #pragma unroll
    for (int nf = 0; nf < 8; nf++) {
        int dd = nf * 16 + l16;
        voff[nf] = ((dd << 2) | (quad ^ ((dd >> 2) & 3))) * 8;
    }

    floatx4 acc[8];
    #pragma unroll
    for (int i = 0; i < 8; i++) acc[i] = (floatx4){0.f, 0.f, 0.f, 0.f};
    float l_part[4] = {0.f, 0.f, 0.f, 0.f};

    int c_r[4];
    #pragma unroll
    for (int r = 0; r < 4; r++) c_r[r] = m0 + quad * 4 + r - l16;  // i_g - l16

    int jlo = i0 - (WIN - 1); if (jlo < 0) jlo = 0;
    const int jt_lo = jlo >> 5;
    const int jt_hi = (i0 + BR - 1) >> 5;

    const float SC2 = 0.08838834764831845f * 1.4426950408889634f;

    const u16* vbase = vtp + (((size_t)hk * NT) << 12);   // 4096 u16 per tile

    const int ch0 = w * 64 + lane;
    auto stage = [&](int bb, int jt) {                    // K only now
        const u16* kpt = kp + ((size_t)(hk * NT + jt)) * TILE_CH * 8;
        #pragma unroll
        for (int it = 0; it < 2; it++) {
            int ch = ch0 + it * 256;
            __builtin_amdgcn_global_load_lds(
                (const __attribute__((address_space(1))) unsigned*)(kpt + ch * 8),
                (__attribute__((address_space(3))) unsigned*)(&Kt[bb][ch * 8]), 16, 0, 0);
        }
    };

    stage(0, jt_lo);
    int bb = 0;

    for (int jt = jt_lo; jt <= jt_hi; jt++) {
        const int j0 = jt << 5;

        __syncthreads();   // drains this wave's global_load_lds (vmcnt(0))

        // V fragments for THIS tile: direct global loads (coalesced 1KB per
        // instruction), issued first so L2 latency hides under QK^T+softmax.
        short8 vf[8];
        {
            const u16* vt = vbase + ((size_t)jt << 12);
            #pragma unroll
            for (int nf = 0; nf < 8; nf++)
                vf[nf] = *(const short8*)(vt + voff[nf]);
        }

        if (jt < jt_hi) stage(bb ^ 1, jt + 1);   // prefetch next K tile

        // ---- QK^T: 8 mfma ----
        floatx4 sc[2];
        sc[0] = (floatx4){0.f, 0.f, 0.f, 0.f};
        sc[1] = (floatx4){0.f, 0.f, 0.f, 0.f};
        #pragma unroll
        for (int kk = 0; kk < 4; kk++) {
            #pragma unroll
            for (int n = 0; n < 2; n++) {
                int row = n * 16 + l16;
                int cc  = kk * 4 + quad;
                int pc  = (row << 4) | (cc ^ (row & 7));
                short8 kf = *(const short8*)(&Kt[bb][pc * 8]);
                sc[n] = __builtin_amdgcn_mfma_f32_16x16x32_bf16(qf[kk], kf, sc[n], 0, 0, 0);
            }
        }

        // ---- softmax: fixed max, pair-interleaved P (col j | col j+16) ----
        const int prow0 = w * 16 + quad * 4;
        const bool interior = (j0 + (BC - 1) <= i0) && (j0 >= i0 + BR - WIN);
        if (interior) {
            #pragma unroll
            for (int r = 0; r < 4; r++) {
                float p0 = exp2f(fmaf(sc[0][r], SC2, -FM));
                float p1 = exp2f(fmaf(sc[1][r], SC2, -FM));
                l_part[r] += p0 + p1;
                *(unsigned*)(&Pb[(prow0 + r) * 40 + l16 * 2]) = cvt_pk(p0, p1);
            }
        } else {
            #pragma unroll
            for (int r = 0; r < 4; r++) {
                bool a0 = (j0 <= c_r[r]) && (j0 > c_r[r] - WIN);
                bool a1 = (j0 + 16 <= c_r[r]) && (j0 + 16 > c_r[r] - WIN);
                float p0 = a0 ? exp2f(fmaf(sc[0][r], SC2, -FM)) : 0.f;
                float p1 = a1 ? exp2f(fmaf(sc[1][r], SC2, -FM)) : 0.f;
                l_part[r] += p0 + p1;
                *(unsigned*)(&Pb[(prow0 + r) * 40 + l16 * 2]) = cvt_pk(p0, p1);
            }
        }

        // ---- PV: 8 mfma (P via same-wave LDS roundtrip, V from registers) ----
        {
            short8 pf = *(const short8*)(&Pb[(w * 16 + l16) * 40 + quad * 8]);
            #pragma unroll
            for (int nf = 0; nf < 8; nf++) {
                acc[nf] = __builtin_amdgcn_mfma_f32_16x16x32_bf16(pf, vf[nf], acc[nf], 0, 0, 0);
            }
        }
        bb ^= 1;
    }

    // ---- epilogue ----
    const float sk2 = exp2f(fmaf(sg[h], 1.4426950408889634f, -FM));
    float inv[4];
    #pragma unroll
    for (int r = 0; r < 4; r++) {
        float l = l_part[r];
        #pragma unroll
        for (int off = 1; off < 16; off <<= 1)
            l += __shfl_xor(l, off);
        inv[r] = 1.f / (l + sk2);
    }
    #pragma unroll
    for (int nf = 0; nf < 8; nf++) {
        int d = nf * 16 + l16;
        #pragma unroll
        for (int r = 0; r < 4; r++) {
            int ig = m0 + quad * 4 + r;
            outg[((size_t)ig * HQ + h) * DH + d] = acc[nf][r] * inv[r];
        }
    }
}

// ---------------- fallback (used only if ws too small; R4 verbatim) ----------------
__launch_bounds__(256, 4)
__global__ void fa_fallback(const float* __restrict__ qg,
                            const float* __restrict__ kg,
                            const float* __restrict__ vg,
                            const float* __restrict__ sg,
                            float* __restrict__ outg)
{
    __shared__ __align__(16) u16 Kt[BC * DH];
    __shared__ __align__(16) u16 Vt[DH * BC];
    __shared__ __align__(16) u16 Pb[BR * 40];

    const int tid  = threadIdx.x;
    const int w    = tid >> 6;
    const int lane = tid & 63;
    const int quad = lane >> 4;
    const int l16  = lane & 15;

    const int qb = blockIdx.x / HQ;
    const int h  = blockIdx.x % HQ;
    const int hk = h >> 2;
    const int i0 = qb * BR;
    const int m0 = i0 + w * 16;

    short8 qf[4];
    {
        const float* qrow = qg + ((size_t)(m0 + l16) * HQ + h) * DH;
        #pragma unroll
        for (int kk = 0; kk < 4; kk++) {
            const float* p = qrow + kk * 32 + quad * 8;
            floatx4 f0 = *(const floatx4*)p;
            floatx4 f1 = *(const floatx4*)(p + 4);
            uintx4 u = (uintx4){rne_pk(f0[0], f0[1]), rne_pk(f0[2], f0[3]),
                                rne_pk(f1[0], f1[1]), rne_pk(f1[2], f1[3])};
            qf[kk] = *(short8*)&u;
        }
    }

    floatx4 acc[8];
    #pragma unroll
    for (int i = 0; i < 8; i++) acc[i] = (floatx4){0.f, 0.f, 0.f, 0.f};
    float l_part[4] = {0.f, 0.f, 0.f, 0.f};

    int jlo = i0 - (WIN - 1); if (jlo < 0) jlo = 0;
    const int jt_lo = jlo >> 5;
    const int jt_hi = (i0 + BR - 1) >> 5;
    const float SC2 = 0.08838834764831845f * 1.4426950408889634f;

    for (int jt = jt_lo; jt <= jt_hi; jt++) {
        const int j0 = jt << 5;
        __syncthreads();
        #pragma unroll
        for (int it = 0; it < 2; it++) {
            int g   = tid + 256 * it;
            int row = g >> 4, cc = g & 15;
            int pc  = (row << 4) | (cc ^ (row & 7));
            const float* kpp = kg + ((size_t)(j0 + row) * HKV + hk) * DH + cc * 8;
            floatx4 f0 = *(const floatx4*)kpp;
            floatx4 f1 = *(const floatx4*)(kpp + 4);
            *(uintx4*)(&Kt[pc * 8]) =
                (uintx4){rne_pk(f0[0], f0[1]), rne_pk(f0[2], f0[3]),
                         rne_pk(f1[0], f1[1]), rne_pk(f1[2], f1[3])};
        }
        #pragma unroll
        for (int it = 0; it < 2; it++) {
            int g  = tid + 256 * it;
            int d  = g & 127, jc = g >> 7;
            const float* vp = vg + ((size_t)(j0 + jc * 8) * HKV + hk) * DH + d;
            float e0 = vp[0 * HKV * DH], e1 = vp[1 * HKV * DH];
            float e2 = vp[2 * HKV * DH], e3 = vp[3 * HKV * DH];
            float e4 = vp[4 * HKV * DH], e5 = vp[5 * HKV * DH];
            float e6 = vp[6 * HKV * DH], e7 = vp[7 * HKV * DH];
            int pc = (d << 2) | (jc ^ ((d >> 2) & 3));
            *(uintx4*)(&Vt[pc * 8]) =
                (uintx4){rne_pk(e0, e1), rne_pk(e2, e3), rne_pk(e4, e5), rne_pk(e6, e7)};
        }
        __syncthreads();

        floatx4 sc[2];
        sc[0] = (floatx4){0.f, 0.f, 0.f, 0.f};
        sc[1] = (floatx4){0.f, 0.f, 0.f, 0.f};
        #pragma unroll
        for (int kk = 0; kk < 4; kk++) {
            #pragma unroll
            for (int n = 0; n < 2; n++) {
                int row = n * 16 + l16;
                int cc  = kk * 4 + quad;
                int pc  = (row << 4) | (cc ^ (row & 7));
                short8 kf = *(const short8*)(&Kt[pc * 8]);
                sc[n] = __builtin_amdgcn_mfma_f32_16x16x32_bf16(qf[kk], kf, sc[n], 0, 0, 0);
            }
        }
        #pragma unroll
        for (int r = 0; r < 4; r++) {
            int   i_g = m0 + quad * 4 + r;
            int   jg0 = j0 + l16, jg1 = j0 + 16 + l16;
            bool  a0  = (jg0 <= i_g) && (i_g - jg0 < WIN);
            bool  a1  = (jg1 <= i_g) && (i_g - jg1 < WIN);
            float p0  = a0 ? exp2f(fmaf(sc[0][r], SC2, -FM)) : 0.f;
            float p1  = a1 ? exp2f(fmaf(sc[1][r], SC2, -FM)) : 0.f;
            l_part[r] += p0 + p1;
            int prow = w * 16 + quad * 4 + r;
            *(unsigned*)(&Pb[prow * 40 + 2 * l16]) = rne_pk(p0, p1);
        }
        {
            short8 pf = *(const short8*)(&Pb[(w * 16 + l16) * 40 + quad * 8]);
            #pragma unroll
            for (int nf = 0; nf < 8; nf++) {
                int dd = nf * 16 + l16;
                int qp = (dd << 2) | (quad ^ ((dd >> 2) & 3));
                short8 vf = *(const short8*)(&Vt[qp * 8]);
                acc[nf] = __builtin_amdgcn_mfma_f32_16x16x32_bf16(pf, vf, acc[nf], 0, 0, 0);
            }
        }
    }

    const float sk2 = exp2f(fmaf(sg[h], 1.4426950408889634f, -FM));
    float inv[4];
    #pragma unroll
    for (int r = 0; r < 4; r++) {
        float l = l_part[r];
        #pragma unroll
        for (int off = 1; off < 16; off <<= 1)
            l += __shfl_xor(l, off);
        inv[r] = 1.f / (l + sk2);
    }
    #pragma unroll
    for (int nf = 0; nf < 8; nf++) {
        int d = nf * 16 + l16;
        #pragma unroll
        for (int r = 0; r < 4; r++) {
            int ig = m0 + quad * 4 + r;
            outg[((size_t)ig * HQ + h) * DH + d] = acc[nf][r] * inv[r];
        }
    }
}

extern "C" void kernel_launch(void* const* d_in, const int* in_sizes, int n_in,
                              void* d_out, int out_size, void* d_ws, size_t ws_size,
                              hipStream_t stream) {
    const float* q  = (const float*)d_in[0];
    const float* k  = (const float*)d_in[1];
    const float* v  = (const float*)d_in[2];
    const float* sk = (const float*)d_in[3];
    float* out = (float*)d_out;

    const size_t tile_elems = (size_t)HKV * NT * TILE_CH * 8;   // u16 elems per tensor
    const size_t need = 2 * tile_elems * sizeof(u16);           // 8 MB

    if (ws_size >= need) {
        u16* kp  = (u16*)d_ws;
        u16* vtp = kp + tile_elems;
        pack_kv<<<dim3(HKV * NT), 256, 0, stream>>>(k, v, kp, vtp);
        fa_kernel<<<dim3((S_LEN / BR) * HQ), 256, 0, stream>>>(q, kp, vtp, sk, out);
    } else {
        fa_fallback<<<dim3((S_LEN / BR) * HQ), 256, 0, stream>>>(q, k, v, sk, out);
    }
}

// Round 7
// 159.147 us; speedup vs baseline: 1.6674x; 1.0966x over previous
//
#include <hip/hip_runtime.h>
#include <hip/hip_bf16.h>

// Flash-attention prefill w/ GQA, causal + sliding-window(1024), attention sink.
// B=1, S=2048, Hq=32, Hkv=8, D=128. fp32 in/out; bf16 MFMA compute, fp32 accum.
// R13: swapped-QK^T with CHAMPION K layout => register-resident P, correctly
// matched to V's interleaved fragment k-mapping.
//   R12 post-mortem: V frag elem 2m <-> j=quad*4+m, elem 2m+1 <-> j=16+quad*4+m
//   (interleaved), but R12 built P assuming straight j=quad*8+e -> wrong.
//   Fix: ss[n] = mfma(kf_n, qf) with UNpermuted rows (n*16+l16, champion
//   swizzle) gives ss[n][r] = S[j0+n*16+quad*4+r][m0+l16]; packing
//   pf elems = cvt_pk(p[0][m], p[1][m]) reproduces the champion Pb layout
//   exactly. Deletes the P LDS roundtrip (4 ds_write + ds_read + lgkmcnt
//   serial wait per iter) -> 4 cvt_pk. Pb gone: LDS = 32KB -> 5 blocks/CU.
//   pack_kv and all LDS addressing byte-identical to champion R4/R6.

#define S_LEN 2048
#define DH    128
#define HQ    32
#define HKV   8
#define WIN   1024
#define BR    64
#define BC    32
#define NT    (S_LEN / BC)          // 64 j-tiles
#define FM    16.0f                 // fixed log2-domain softmax max
#define TILE_CH 512                 // 16B chunks per 32x128 bf16 tile

typedef unsigned short u16;
typedef __attribute__((ext_vector_type(8))) short  short8;
typedef __attribute__((ext_vector_type(4))) float  floatx4;
typedef __attribute__((ext_vector_type(4))) unsigned int uintx4;

__device__ __forceinline__ unsigned rne1(float a) {
    unsigned u = __float_as_uint(a);
    return (u + 0x7FFFu + ((u >> 16) & 1u)) >> 16;
}
__device__ __forceinline__ unsigned rne_pk(float a, float b) {
    return rne1(a) | (rne1(b) << 16);
}
// single-instruction RNE pack (same rounding as rne_pk; validated R8/R9/R11)
__device__ __forceinline__ unsigned cvt_pk(float a, float b) {
    unsigned r;
    asm("v_cvt_pk_bf16_f32 %0, %1, %2" : "=v"(r) : "v"(a), "v"(b));
    return r;
}

// ---------------- pre-pass: pack K/V^T to bf16 in ws (champion verbatim) --------
__global__ __launch_bounds__(256) void pack_kv(const float* __restrict__ kg,
                                               const float* __restrict__ vg,
                                               u16* __restrict__ kp,
                                               u16* __restrict__ vtp)
{
    __shared__ float Vs[BC][DH + 1];
    const int b   = blockIdx.x;
    const int hk  = b >> 6;
    const int jt  = b & 63;
    const int tid = threadIdx.x;
    const int j0  = jt * BC;

    #pragma unroll
    for (int t = 0; t < 4; t++) {
        int idx = tid + t * 256;        // float4 id 0..1023
        int j   = idx >> 5;
        int dc  = idx & 31;
        floatx4 f = *(const floatx4*)(vg + ((size_t)(j0 + j) * HKV + hk) * DH + dc * 4);
        Vs[j][dc * 4 + 0] = f[0]; Vs[j][dc * 4 + 1] = f[1];
        Vs[j][dc * 4 + 2] = f[2]; Vs[j][dc * 4 + 3] = f[3];
    }

    u16* kpt = kp + (size_t)b * TILE_CH * 8;
    #pragma unroll
    for (int t = 0; t < 2; t++) {
        int c = tid + t * 256;
        int row = c >> 4, cc = c & 15;
        const float* p = kg + ((size_t)(j0 + row) * HKV + hk) * DH + cc * 8;
        floatx4 f0 = *(const floatx4*)p;
        floatx4 f1 = *(const floatx4*)(p + 4);
        int pc = (row << 4) | (cc ^ (row & 7));
        *(uintx4*)(kpt + pc * 8) =
            (uintx4){rne_pk(f0[0], f0[1]), rne_pk(f0[2], f0[3]),
                     rne_pk(f1[0], f1[1]), rne_pk(f1[2], f1[3])};
    }
    __syncthreads();

    u16* vpt = vtp + (size_t)b * TILE_CH * 8;
    #pragma unroll
    for (int t = 0; t < 2; t++) {
        int q  = tid + t * 256;
        int dd = q >> 2, c = q & 3;
        unsigned w0 = rne_pk(Vs[c * 4 + 0][dd], Vs[c * 4 + 16][dd]);
        unsigned w1 = rne_pk(Vs[c * 4 + 1][dd], Vs[c * 4 + 17][dd]);
        unsigned w2 = rne_pk(Vs[c * 4 + 2][dd], Vs[c * 4 + 18][dd]);
        unsigned w3 = rne_pk(Vs[c * 4 + 3][dd], Vs[c * 4 + 19][dd]);
        int qp = (dd << 2) | (c ^ ((dd >> 2) & 3));
        *(uintx4*)(vpt + qp * 8) = (uintx4){w0, w1, w2, w3};
    }
}

// -------- main flash kernel (R13: swapped QK^T, register-resident P) --------
__launch_bounds__(256, 5)
__global__ void fa_kernel(const float* __restrict__ qg,
                          const u16* __restrict__ kp,
                          const u16* __restrict__ vtp,
                          const float* __restrict__ sg,
                          float* __restrict__ outg)
{
    __shared__ __align__(16) u16 Kt[2][TILE_CH * 8];   // 2 x 8 KB
    __shared__ __align__(16) u16 Vt[2][TILE_CH * 8];   // 2 x 8 KB  (total 32 KB)

    const int tid  = threadIdx.x;
    const int w    = tid >> 6;
    const int lane = tid & 63;
    const int quad = lane >> 4;
    const int l16  = lane & 15;

    // R6 mapping: hk = bid&7 (XCD-local KV); per-CU-slot qb set is balanced.
    const int bid  = blockIdx.x;
    const int hk   = bid & 7;
    const int idx  = bid >> 3;          // 0..127 within this hk
    const int hrem = idx & 3;
    const int u5   = (idx >> 2) & 7;
    const int t4   = idx >> 5;          // 0..3
    const int qbt[4] = {u5, 15 - u5, 16 + u5, 31 - u5};
    const int qb   = qbt[t4];
    const int h    = hk * 4 + hrem;

    const int i0 = qb * BR;
    const int m0 = i0 + w * 16;

    // ---- Q fragments (B-operand of swapped QK^T; same per-lane layout) ----
    short8 qf[4];
    {
        const float* qrow = qg + ((size_t)(m0 + l16) * HQ + h) * DH;
        #pragma unroll
        for (int kk = 0; kk < 4; kk++) {
            const float* p = qrow + kk * 32 + quad * 8;
            floatx4 f0 = *(const floatx4*)p;
            floatx4 f1 = *(const floatx4*)(p + 4);
            uintx4 uq = (uintx4){cvt_pk(f0[0], f0[1]), cvt_pk(f0[2], f0[3]),
                                 cvt_pk(f1[0], f1[1]), cvt_pk(f1[2], f1[3])};
            qf[kk] = *(short8*)&uq;
        }
    }

    // ---- precompute LDS offsets (u16 units), loop-invariant ----
    // K: chain n reads row n*16+l16, chunk cc=kk*4+quad (champion addressing).
    int kpc[8];
    #pragma unroll
    for (int n = 0; n < 2; n++) {
        int row = n * 16 + l16;
        #pragma unroll
        for (int kk = 0; kk < 4; kk++)
            kpc[n * 4 + kk] = (((row << 4) | ((kk * 4 + quad) ^ (row & 7)))) * 8;
    }
    // V: champion fragment addressing (hoisted)
    int vqp[8];
    #pragma unroll
    for (int nf = 0; nf < 8; nf++) {
        int dd = nf * 16 + l16;
        vqp[nf] = ((dd << 2) | (quad ^ ((dd >> 2) & 3))) * 8;
    }

    floatx4 acc[8];
    #pragma unroll
    for (int i = 0; i < 8; i++) acc[i] = (floatx4){0.f, 0.f, 0.f, 0.f};
    float l_sum = 0.f;                 // denominator partial for Q-row (m0+l16)

    const int ci  = m0 + l16;          // this lane's Q row (global index)
    const int qb4 = quad * 4;          // j sub-base within tile

    int jlo = i0 - (WIN - 1); if (jlo < 0) jlo = 0;
    const int jt_lo = jlo >> 5;
    const int jt_hi = (i0 + BR - 1) >> 5;

    const float SC2 = 0.08838834764831845f * 1.4426950408889634f;

    const int ch0 = w * 64 + lane;
    auto stage = [&](int bb, int jt) {
        const u16* kpt = kp  + ((size_t)(hk * NT + jt)) * TILE_CH * 8;
        const u16* vpt = vtp + ((size_t)(hk * NT + jt)) * TILE_CH * 8;
        #pragma unroll
        for (int it = 0; it < 2; it++) {
            int ch = ch0 + it * 256;
            __builtin_amdgcn_global_load_lds(
                (const __attribute__((address_space(1))) unsigned*)(kpt + ch * 8),
                (__attribute__((address_space(3))) unsigned*)(&Kt[bb][ch * 8]), 16, 0, 0);
            __builtin_amdgcn_global_load_lds(
                (const __attribute__((address_space(1))) unsigned*)(vpt + ch * 8),
                (__attribute__((address_space(3))) unsigned*)(&Vt[bb][ch * 8]), 16, 0, 0);
        }
    };

    stage(0, jt_lo);
    int bb = 0;

    for (int jt = jt_lo; jt <= jt_hi; jt++) {
        const int j0 = jt << 5;

        __syncthreads();   // drains this wave's global_load_lds (vmcnt(0))

        if (jt < jt_hi) stage(bb ^ 1, jt + 1);   // prefetch next tile

        // ---- swapped QK^T: ss[n][r] = S[j0 + n*16 + qb4 + r][ci], 8 mfma ----
        floatx4 ss[2];
        ss[0] = (floatx4){0.f, 0.f, 0.f, 0.f};
        ss[1] = (floatx4){0.f, 0.f, 0.f, 0.f};
        #pragma unroll
        for (int kk = 0; kk < 4; kk++) {
            short8 kf0 = *(const short8*)(&Kt[bb][kpc[kk]]);
            short8 kf1 = *(const short8*)(&Kt[bb][kpc[4 + kk]]);
            ss[0] = __builtin_amdgcn_mfma_f32_16x16x32_bf16(kf0, qf[kk], ss[0], 0, 0, 0);
            ss[1] = __builtin_amdgcn_mfma_f32_16x16x32_bf16(kf1, qf[kk], ss[1], 0, 0, 0);
        }

        // ---- softmax (fixed max); P stays in registers ----
        float p[2][4];
        const bool interior = (j0 + (BC - 1) <= i0) && (j0 >= i0 + BR - WIN);
        if (interior) {
            #pragma unroll
            for (int n = 0; n < 2; n++)
                #pragma unroll
                for (int r = 0; r < 4; r++)
                    p[n][r] = exp2f(fmaf(ss[n][r], SC2, -FM));
        } else {
            const int dj = ci - j0;        // allowed: t <= dj && t > dj-WIN
            #pragma unroll
            for (int n = 0; n < 2; n++)
                #pragma unroll
                for (int r = 0; r < 4; r++) {
                    int t = n * 16 + qb4 + r;
                    bool a = (t <= dj) && (t > dj - WIN);
                    p[n][r] = a ? exp2f(fmaf(ss[n][r], SC2, -FM)) : 0.f;
                }
        }
        l_sum += ((p[0][0] + p[0][1]) + (p[0][2] + p[0][3]))
               + ((p[1][0] + p[1][1]) + (p[1][2] + p[1][3]));

        // ---- P -> A-fragment: interleave chain0/chain1 to match V's k-map ----
        // elem 2m = P[ci][j0+qb4+m] (chain 0), elem 2m+1 = P[ci][j0+16+qb4+m].
        uintx4 upf = (uintx4){cvt_pk(p[0][0], p[1][0]), cvt_pk(p[0][1], p[1][1]),
                              cvt_pk(p[0][2], p[1][2]), cvt_pk(p[0][3], p[1][3])};
        short8 pf = *(short8*)&upf;

        // ---- PV: 8 mfma, V from LDS (champion addressing) ----
        #pragma unroll
        for (int nf = 0; nf < 8; nf++) {
            short8 vf = *(const short8*)(&Vt[bb][vqp[nf]]);
            acc[nf] = __builtin_amdgcn_mfma_f32_16x16x32_bf16(pf, vf, acc[nf], 0, 0, 0);
        }
        bb ^= 1;
    }

    // ---- epilogue ----
    // Full denominator for Q-row (m0+l16): sum l_sum across the 4 quads.
    l_sum += __shfl_xor(l_sum, 16);
    l_sum += __shfl_xor(l_sum, 32);
    const float sk2 = exp2f(fmaf(sg[h], 1.4426950408889634f, -FM));
    float inv_r[4];
    #pragma unroll
    for (int r = 0; r < 4; r++) {
        float Lr = __shfl(l_sum, qb4 + r);   // lane qb4+r holds row m0+qb4+r's L
        inv_r[r] = 1.f / (Lr + sk2);
    }
    #pragma unroll
    for (int nf = 0; nf < 8; nf++) {
        int d = nf * 16 + l16;
        #pragma unroll
        for (int r = 0; r < 4; r++) {
            int ig = m0 + qb4 + r;
            outg[((size_t)ig * HQ + h) * DH + d] = acc[nf][r] * inv_r[r];
        }
    }
}

// ---------------- fallback (used only if ws too small; champion verbatim) --------
__launch_bounds__(256, 4)
__global__ void fa_fallback(const float* __restrict__ qg,
                            const float* __restrict__ kg,
                            const float* __restrict__ vg,
                            const float* __restrict__ sg,
                            float* __restrict__ outg)
{
    __shared__ __align__(16) u16 Kt[BC * DH];
    __shared__ __align__(16) u16 Vt[DH * BC];
    __shared__ __align__(16) u16 Pb[BR * 40];

    const int tid  = threadIdx.x;
    const int w    = tid >> 6;
    const int lane = tid & 63;
    const int quad = lane >> 4;
    const int l16  = lane & 15;

    const int qb = blockIdx.x / HQ;
    const int h  = blockIdx.x % HQ;
    const int hk = h >> 2;
    const int i0 = qb * BR;
    const int m0 = i0 + w * 16;

    short8 qf[4];
    {
        const float* qrow = qg + ((size_t)(m0 + l16) * HQ + h) * DH;
        #pragma unroll
        for (int kk = 0; kk < 4; kk++) {
            const float* p = qrow + kk * 32 + quad * 8;
            floatx4 f0 = *(const floatx4*)p;
            floatx4 f1 = *(const floatx4*)(p + 4);
            uintx4 u = (uintx4){rne_pk(f0[0], f0[1]), rne_pk(f0[2], f0[3]),
                                rne_pk(f1[0], f1[1]), rne_pk(f1[2], f1[3])};
            qf[kk] = *(short8*)&u;
        }
    }

    floatx4 acc[8];
    #pragma unroll
    for (int i = 0; i < 8; i++) acc[i] = (floatx4){0.f, 0.f, 0.f, 0.f};
    float l_part[4] = {0.f, 0.f, 0.f, 0.f};

    int jlo = i0 - (WIN - 1); if (jlo < 0) jlo = 0;
    const int jt_lo = jlo >> 5;
    const int jt_hi = (i0 + BR - 1) >> 5;
    const float SC2 = 0.08838834764831845f * 1.4426950408889634f;

    for (int jt = jt_lo; jt <= jt_hi; jt++) {
        const int j0 = jt << 5;
        __syncthreads();
        #pragma unroll
        for (int it = 0; it < 2; it++) {
            int g   = tid + 256 * it;
            int row = g >> 4, cc = g & 15;
            int pc  = (row << 4) | (cc ^ (row & 7));
            const float* kpp = kg + ((size_t)(j0 + row) * HKV + hk) * DH + cc * 8;
            floatx4 f0 = *(const floatx4*)kpp;
            floatx4 f1 = *(const floatx4*)(kpp + 4);
            *(uintx4*)(&Kt[pc * 8]) =
                (uintx4){rne_pk(f0[0], f0[1]), rne_pk(f0[2], f0[3]),
                         rne_pk(f1[0], f1[1]), rne_pk(f1[2], f1[3])};
        }
        #pragma unroll
        for (int it = 0; it < 2; it++) {
            int g  = tid + 256 * it;
            int d  = g & 127, jc = g >> 7;
            const float* vp = vg + ((size_t)(j0 + jc * 8) * HKV + hk) * DH + d;
            float e0 = vp[0 * HKV * DH], e1 = vp[1 * HKV * DH];
            float e2 = vp[2 * HKV * DH], e3 = vp[3 * HKV * DH];
            float e4 = vp[4 * HKV * DH], e5 = vp[5 * HKV * DH];
            float e6 = vp[6 * HKV * DH], e7 = vp[7 * HKV * DH];
            int pc = (d << 2) | (jc ^ ((d >> 2) & 3));
            *(uintx4*)(&Vt[pc * 8]) =
                (uintx4){rne_pk(e0, e1), rne_pk(e2, e3), rne_pk(e4, e5), rne_pk(e6, e7)};
        }
        __syncthreads();

        floatx4 sc[2];
        sc[0] = (floatx4){0.f, 0.f, 0.f, 0.f};
        sc[1] = (floatx4){0.f, 0.f, 0.f, 0.f};
        #pragma unroll
        for (int kk = 0; kk < 4; kk++) {
            #pragma unroll
            for (int n = 0; n < 2; n++) {
                int row = n * 16 + l16;
                int cc  = kk * 4 + quad;
                int pc  = (row << 4) | (cc ^ (row & 7));
                short8 kf = *(const short8*)(&Kt[pc * 8]);
                sc[n] = __builtin_amdgcn_mfma_f32_16x16x32_bf16(qf[kk], kf, sc[n], 0, 0, 0);
            }
        }
        #pragma unroll
        for (int r = 0; r < 4; r++) {
            int   i_g = m0 + quad * 4 + r;
            int   jg0 = j0 + l16, jg1 = j0 + 16 + l16;
            bool  a0  = (jg0 <= i_g) && (i_g - jg0 < WIN);
            bool  a1  = (jg1 <= i_g) && (i_g - jg1 < WIN);
            float p0  = a0 ? exp2f(fmaf(sc[0][r], SC2, -FM)) : 0.f;
            float p1  = a1 ? exp2f(fmaf(sc[1][r], SC2, -FM)) : 0.f;
            l_part[r] += p0 + p1;
            int prow = w * 16 + quad * 4 + r;
            *(unsigned*)(&Pb[prow * 40 + 2 * l16]) = rne_pk(p0, p1);
        }
        {
            short8 pf = *(const short8*)(&Pb[(w * 16 + l16) * 40 + quad * 8]);
            #pragma unroll
            for (int nf = 0; nf < 8; nf++) {
                int dd = nf * 16 + l16;
                int qp = (dd << 2) | (quad ^ ((dd >> 2) & 3));
                short8 vf = *(const short8*)(&Vt[qp * 8]);
                acc[nf] = __builtin_amdgcn_mfma_f32_16x16x32_bf16(pf, vf, acc[nf], 0, 0, 0);
            }
        }
    }

    const float sk2 = exp2f(fmaf(sg[h], 1.4426950408889634f, -FM));
    float inv[4];
    #pragma unroll
    for (int r = 0; r < 4; r++) {
        float l = l_part[r];
        #pragma unroll
        for (int off = 1; off < 16; off <<= 1)
            l += __shfl_xor(l, off);
        inv[r] = 1.f / (l + sk2);
    }
    #pragma unroll
    for (int nf = 0; nf < 8; nf++) {
        int d = nf * 16 + l16;
        #pragma unroll
        for (int r = 0; r < 4; r++) {
            int ig = m0 + quad * 4 + r;
            outg[((size_t)ig * HQ + h) * DH + d] = acc[nf][r] * inv[r];
        }
    }
}

extern "C" void kernel_launch(void* const* d_in, const int* in_sizes, int n_in,
                              void* d_out, int out_size, void* d_ws, size_t ws_size,
                              hipStream_t stream) {
    const float* q  = (const float*)d_in[0];
    const float* k  = (const float*)d_in[1];
    const float* v  = (const float*)d_in[2];
    const float* sk = (const float*)d_in[3];
    float* out = (float*)d_out;

    const size_t tile_elems = (size_t)HKV * NT * TILE_CH * 8;   // u16 elems per tensor
    const size_t need = 2 * tile_elems * sizeof(u16);           // 8 MB

    if (ws_size >= need) {
        u16* kp  = (u16*)d_ws;
        u16* vtp = kp + tile_elems;
        pack_kv<<<dim3(HKV * NT), 256, 0, stream>>>(k, v, kp, vtp);
        fa_kernel<<<dim3((S_LEN / BR) * HQ), 256, 0, stream>>>(q, kp, vtp, sk, out);
    } else {
        fa_fallback<<<dim3((S_LEN / BR) * HQ), 256, 0, stream>>>(q, k, v, sk, out);
    }
}

// Round 8
// 155.830 us; speedup vs baseline: 1.7029x; 1.0213x over previous
//
#include <hip/hip_runtime.h>
#include <hip/hip_bf16.h>

// Flash-attention prefill w/ GQA, causal + sliding-window(1024), attention sink.
// B=1, S=2048, Hq=32, Hkv=8, D=128. fp32 in/out; bf16 MFMA compute, fp32 accum.
// R14: fragment-ordered K/V packing => conflict-free LDS reads.
//   R13 counters: LDS pipe ~87% busy, SQ_LDS_BANK_CONFLICT 6.68M ~ 19% of wall.
//   The (instr, lane) -> (row, chunk) fragment map is a bijection for both K
//   and V, and read offsets are wave-independent. So pack kp/vtp in FRAGMENT
//   ORDER: chunk_new = instr*64 + lane. Every ds_read_b128 becomes
//   base + lane*16B (linear, the inverse of the conflict-free DMA write
//   pattern) -> zero bank conflicts by construction. Values, MFMA math,
//   staging, and all other structure identical to R13 (register-resident P,
//   swapped QK^T, 5 blocks/CU, 32KB LDS).

#define S_LEN 2048
#define DH    128
#define HQ    32
#define HKV   8
#define WIN   1024
#define BR    64
#define BC    32
#define NT    (S_LEN / BC)          // 64 j-tiles
#define FM    16.0f                 // fixed log2-domain softmax max
#define TILE_CH 512                 // 16B chunks per 32x128 bf16 tile

typedef unsigned short u16;
typedef __attribute__((ext_vector_type(8))) short  short8;
typedef __attribute__((ext_vector_type(4))) float  floatx4;
typedef __attribute__((ext_vector_type(4))) unsigned int uintx4;

__device__ __forceinline__ unsigned rne1(float a) {
    unsigned u = __float_as_uint(a);
    return (u + 0x7FFFu + ((u >> 16) & 1u)) >> 16;
}
__device__ __forceinline__ unsigned rne_pk(float a, float b) {
    return rne1(a) | (rne1(b) << 16);
}
// single-instruction RNE pack (same rounding as rne_pk; validated R8-R13)
__device__ __forceinline__ unsigned cvt_pk(float a, float b) {
    unsigned r;
    asm("v_cvt_pk_bf16_f32 %0, %1, %2" : "=v"(r) : "v"(a), "v"(b));
    return r;
}

// ---------------- pre-pass: pack K/V^T to bf16 in ws ----------------
// R14 fragment-ordered layout:
//   K (row, cc):  instr = (row>>4)*4 + (cc>>2), lane = (cc&3)*16 + (row&15)
//                 chunk = instr*64 + lane
//   V (dd, c):    instr = dd>>4,               lane = c*16 + (dd&15)
//                 chunk = instr*64 + lane
__global__ __launch_bounds__(256) void pack_kv(const float* __restrict__ kg,
                                               const float* __restrict__ vg,
                                               u16* __restrict__ kp,
                                               u16* __restrict__ vtp)
{
    __shared__ float Vs[BC][DH + 1];
    const int b   = blockIdx.x;
    const int hk  = b >> 6;
    const int jt  = b & 63;
    const int tid = threadIdx.x;
    const int j0  = jt * BC;

    #pragma unroll
    for (int t = 0; t < 4; t++) {
        int idx = tid + t * 256;        // float4 id 0..1023
        int j   = idx >> 5;
        int dc  = idx & 31;
        floatx4 f = *(const floatx4*)(vg + ((size_t)(j0 + j) * HKV + hk) * DH + dc * 4);
        Vs[j][dc * 4 + 0] = f[0]; Vs[j][dc * 4 + 1] = f[1];
        Vs[j][dc * 4 + 2] = f[2]; Vs[j][dc * 4 + 3] = f[3];
    }

    u16* kpt = kp + (size_t)b * TILE_CH * 8;
    #pragma unroll
    for (int t = 0; t < 2; t++) {
        int c = tid + t * 256;
        int row = c >> 4, cc = c & 15;
        const float* p = kg + ((size_t)(j0 + row) * HKV + hk) * DH + cc * 8;
        floatx4 f0 = *(const floatx4*)p;
        floatx4 f1 = *(const floatx4*)(p + 4);
        int pc = (((row >> 4) * 4 + (cc >> 2)) << 6) | ((cc & 3) << 4) | (row & 15);
        *(uintx4*)(kpt + pc * 8) =
            (uintx4){rne_pk(f0[0], f0[1]), rne_pk(f0[2], f0[3]),
                     rne_pk(f1[0], f1[1]), rne_pk(f1[2], f1[3])};
    }
    __syncthreads();

    u16* vpt = vtp + (size_t)b * TILE_CH * 8;
    #pragma unroll
    for (int t = 0; t < 2; t++) {
        int q  = tid + t * 256;
        int dd = q >> 2, c = q & 3;
        unsigned w0 = rne_pk(Vs[c * 4 + 0][dd], Vs[c * 4 + 16][dd]);
        unsigned w1 = rne_pk(Vs[c * 4 + 1][dd], Vs[c * 4 + 17][dd]);
        unsigned w2 = rne_pk(Vs[c * 4 + 2][dd], Vs[c * 4 + 18][dd]);
        unsigned w3 = rne_pk(Vs[c * 4 + 3][dd], Vs[c * 4 + 19][dd]);
        int qp = ((dd >> 4) << 6) | (c << 4) | (dd & 15);
        *(uintx4*)(vpt + qp * 8) = (uintx4){w0, w1, w2, w3};
    }
}

// -------- main flash kernel (R14: R13 + conflict-free fragment-ordered LDS) -----
__launch_bounds__(256, 5)
__global__ void fa_kernel(const float* __restrict__ qg,
                          const u16* __restrict__ kp,
                          const u16* __restrict__ vtp,
                          const float* __restrict__ sg,
                          float* __restrict__ outg)
{
    __shared__ __align__(16) u16 Kt[2][TILE_CH * 8];   // 2 x 8 KB
    __shared__ __align__(16) u16 Vt[2][TILE_CH * 8];   // 2 x 8 KB  (total 32 KB)

    const int tid  = threadIdx.x;
    const int w    = tid >> 6;
    const int lane = tid & 63;
    const int quad = lane >> 4;
    const int l16  = lane & 15;

    // R6 mapping: hk = bid&7 (XCD-local KV); per-CU-slot qb set is balanced.
    const int bid  = blockIdx.x;
    const int hk   = bid & 7;
    const int idx  = bid >> 3;          // 0..127 within this hk
    const int hrem = idx & 3;
    const int u5   = (idx >> 2) & 7;
    const int t4   = idx >> 5;          // 0..3
    const int qbt[4] = {u5, 15 - u5, 16 + u5, 31 - u5};
    const int qb   = qbt[t4];
    const int h    = hk * 4 + hrem;

    const int i0 = qb * BR;
    const int m0 = i0 + w * 16;

    // ---- Q fragments (B-operand of swapped QK^T) ----
    short8 qf[4];
    {
        const float* qrow = qg + ((size_t)(m0 + l16) * HQ + h) * DH;
        #pragma unroll
        for (int kk = 0; kk < 4; kk++) {
            const float* p = qrow + kk * 32 + quad * 8;
            floatx4 f0 = *(const floatx4*)p;
            floatx4 f1 = *(const floatx4*)(p + 4);
            uintx4 uq = (uintx4){cvt_pk(f0[0], f0[1]), cvt_pk(f0[2], f0[3]),
                                 cvt_pk(f1[0], f1[1]), cvt_pk(f1[2], f1[3])};
            qf[kk] = *(short8*)&uq;
        }
    }

    // ---- fragment-ordered LDS offsets: instr i reads chunk i*64 + lane ----
    // K instr i = n*4+kk holds K[n*16+l16][(kk*4+quad)*8 ..], lane = quad*16+l16.
    // V instr nf holds (V[quad*4+m][nf*16+l16], V[16+quad*4+m][nf*16+l16]) pairs.
    const int lane8 = lane * 8;         // u16 offset of this lane within a frag row

    floatx4 acc[8];
    #pragma unroll
    for (int i = 0; i < 8; i++) acc[i] = (floatx4){0.f, 0.f, 0.f, 0.f};
    float l_sum = 0.f;                 // denominator partial for Q-row (m0+l16)

    const int ci  = m0 + l16;          // this lane's Q row (global index)
    const int qb4 = quad * 4;          // j sub-base within tile

    int jlo = i0 - (WIN - 1); if (jlo < 0) jlo = 0;
    const int jt_lo = jlo >> 5;
    const int jt_hi = (i0 + BR - 1) >> 5;

    const float SC2 = 0.08838834764831845f * 1.4426950408889634f;

    const int ch0 = w * 64 + lane;
    auto stage = [&](int bb, int jt) {
        const u16* kpt = kp  + ((size_t)(hk * NT + jt)) * TILE_CH * 8;
        const u16* vpt = vtp + ((size_t)(hk * NT + jt)) * TILE_CH * 8;
        #pragma unroll
        for (int it = 0; it < 2; it++) {
            int ch = ch0 + it * 256;
            __builtin_amdgcn_global_load_lds(
                (const __attribute__((address_space(1))) unsigned*)(kpt + ch * 8),
                (__attribute__((address_space(3))) unsigned*)(&Kt[bb][ch * 8]), 16, 0, 0);
            __builtin_amdgcn_global_load_lds(
                (const __attribute__((address_space(1))) unsigned*)(vpt + ch * 8),
                (__attribute__((address_space(3))) unsigned*)(&Vt[bb][ch * 8]), 16, 0, 0);
        }
    };

    stage(0, jt_lo);
    int bb = 0;

    for (int jt = jt_lo; jt <= jt_hi; jt++) {
        const int j0 = jt << 5;

        __syncthreads();   // drains this wave's global_load_lds (vmcnt(0))

        if (jt < jt_hi) stage(bb ^ 1, jt + 1);   // prefetch next tile

        // ---- swapped QK^T: ss[n][r] = S[j0 + n*16 + qb4 + r][ci], 8 mfma ----
        floatx4 ss[2];
        ss[0] = (floatx4){0.f, 0.f, 0.f, 0.f};
        ss[1] = (floatx4){0.f, 0.f, 0.f, 0.f};
        #pragma unroll
        for (int kk = 0; kk < 4; kk++) {
            short8 kf0 = *(const short8*)(&Kt[bb][(kk << 9) + lane8]);          // instr kk
            short8 kf1 = *(const short8*)(&Kt[bb][((4 + kk) << 9) + lane8]);    // instr 4+kk
            ss[0] = __builtin_amdgcn_mfma_f32_16x16x32_bf16(kf0, qf[kk], ss[0], 0, 0, 0);
            ss[1] = __builtin_amdgcn_mfma_f32_16x16x32_bf16(kf1, qf[kk], ss[1], 0, 0, 0);
        }

        // ---- softmax (fixed max); P stays in registers ----
        float p[2][4];
        const bool interior = (j0 + (BC - 1) <= i0) && (j0 >= i0 + BR - WIN);
        if (interior) {
            #pragma unroll
            for (int n = 0; n < 2; n++)
                #pragma unroll
                for (int r = 0; r < 4; r++)
                    p[n][r] = exp2f(fmaf(ss[n][r], SC2, -FM));
        } else {
            const int dj = ci - j0;        // allowed: t <= dj && t > dj-WIN
            #pragma unroll
            for (int n = 0; n < 2; n++)
                #pragma unroll
                for (int r = 0; r < 4; r++) {
                    int t = n * 16 + qb4 + r;
                    bool a = (t <= dj) && (t > dj - WIN);
                    p[n][r] = a ? exp2f(fmaf(ss[n][r], SC2, -FM)) : 0.f;
                }
        }
        l_sum += ((p[0][0] + p[0][1]) + (p[0][2] + p[0][3]))
               + ((p[1][0] + p[1][1]) + (p[1][2] + p[1][3]));

        // ---- P -> A-fragment: interleave chain0/chain1 to match V's k-map ----
        uintx4 upf = (uintx4){cvt_pk(p[0][0], p[1][0]), cvt_pk(p[0][1], p[1][1]),
                              cvt_pk(p[0][2], p[1][2]), cvt_pk(p[0][3], p[1][3])};
        short8 pf = *(short8*)&upf;

        // ---- PV: 8 mfma, V from LDS (fragment-ordered, conflict-free) ----
        #pragma unroll
        for (int nf = 0; nf < 8; nf++) {
            short8 vf = *(const short8*)(&Vt[bb][(nf << 9) + lane8]);
            acc[nf] = __builtin_amdgcn_mfma_f32_16x16x32_bf16(pf, vf, acc[nf], 0, 0, 0);
        }
        bb ^= 1;
    }

    // ---- epilogue ----
    l_sum += __shfl_xor(l_sum, 16);
    l_sum += __shfl_xor(l_sum, 32);
    const float sk2 = exp2f(fmaf(sg[h], 1.4426950408889634f, -FM));
    float inv_r[4];
    #pragma unroll
    for (int r = 0; r < 4; r++) {
        float Lr = __shfl(l_sum, qb4 + r);   // lane qb4+r holds row m0+qb4+r's L
        inv_r[r] = 1.f / (Lr + sk2);
    }
    #pragma unroll
    for (int nf = 0; nf < 8; nf++) {
        int d = nf * 16 + l16;
        #pragma unroll
        for (int r = 0; r < 4; r++) {
            int ig = m0 + qb4 + r;
            outg[((size_t)ig * HQ + h) * DH + d] = acc[nf][r] * inv_r[r];
        }
    }
}

// ---------------- fallback (used only if ws too small; champion verbatim) --------
__launch_bounds__(256, 4)
__global__ void fa_fallback(const float* __restrict__ qg,
                            const float* __restrict__ kg,
                            const float* __restrict__ vg,
                            const float* __restrict__ sg,
                            float* __restrict__ outg)
{
    __shared__ __align__(16) u16 Kt[BC * DH];
    __shared__ __align__(16) u16 Vt[DH * BC];
    __shared__ __align__(16) u16 Pb[BR * 40];

    const int tid  = threadIdx.x;
    const int w    = tid >> 6;
    const int lane = tid & 63;
    const int quad = lane >> 4;
    const int l16  = lane & 15;

    const int qb = blockIdx.x / HQ;
    const int h  = blockIdx.x % HQ;
    const int hk = h >> 2;
    const int i0 = qb * BR;
    const int m0 = i0 + w * 16;

    short8 qf[4];
    {
        const float* qrow = qg + ((size_t)(m0 + l16) * HQ + h) * DH;
        #pragma unroll
        for (int kk = 0; kk < 4; kk++) {
            const float* p = qrow + kk * 32 + quad * 8;
            floatx4 f0 = *(const floatx4*)p;
            floatx4 f1 = *(const floatx4*)(p + 4);
            uintx4 u = (uintx4){rne_pk(f0[0], f0[1]), rne_pk(f0[2], f0[3]),
                                rne_pk(f1[0], f1[1]), rne_pk(f1[2], f1[3])};
            qf[kk] = *(short8*)&u;
        }
    }

    floatx4 acc[8];
    #pragma unroll
    for (int i = 0; i < 8; i++) acc[i] = (floatx4){0.f, 0.f, 0.f, 0.f};
    float l_part[4] = {0.f, 0.f, 0.f, 0.f};

    int jlo = i0 - (WIN - 1); if (jlo < 0) jlo = 0;
    const int jt_lo = jlo >> 5;
    const int jt_hi = (i0 + BR - 1) >> 5;
    const float SC2 = 0.08838834764831845f * 1.4426950408889634f;

    for (int jt = jt_lo; jt <= jt_hi; jt++) {
        const int j0 = jt << 5;
        __syncthreads();
        #pragma unroll
        for (int it = 0; it < 2; it++) {
            int g   = tid + 256 * it;
            int row = g >> 4, cc = g & 15;
            int pc  = (row << 4) | (cc ^ (row & 7));
            const float* kpp = kg + ((size_t)(j0 + row) * HKV + hk) * DH + cc * 8;
            floatx4 f0 = *(const floatx4*)kpp;
            floatx4 f1 = *(const floatx4*)(kpp + 4);
            *(uintx4*)(&Kt[pc * 8]) =
                (uintx4){rne_pk(f0[0], f0[1]), rne_pk(f0[2], f0[3]),
                         rne_pk(f1[0], f1[1]), rne_pk(f1[2], f1[3])};
        }
        #pragma unroll
        for (int it = 0; it < 2; it++) {
            int g  = tid + 256 * it;
            int d  = g & 127, jc = g >> 7;
            const float* vp = vg + ((size_t)(j0 + jc * 8) * HKV + hk) * DH + d;
            float e0 = vp[0 * HKV * DH], e1 = vp[1 * HKV * DH];
            float e2 = vp[2 * HKV * DH], e3 = vp[3 * HKV * DH];
            float e4 = vp[4 * HKV * DH], e5 = vp[5 * HKV * DH];
            float e6 = vp[6 * HKV * DH], e7 = vp[7 * HKV * DH];
            int pc = (d << 2) | (jc ^ ((d >> 2) & 3));
            *(uintx4*)(&Vt[pc * 8]) =
                (uintx4){rne_pk(e0, e1), rne_pk(e2, e3), rne_pk(e4, e5), rne_pk(e6, e7)};
        }
        __syncthreads();

        floatx4 sc[2];
        sc[0] = (floatx4){0.f, 0.f, 0.f, 0.f};
        sc[1] = (floatx4){0.f, 0.f, 0.f, 0.f};
        #pragma unroll
        for (int kk = 0; kk < 4; kk++) {
            #pragma unroll
            for (int n = 0; n < 2; n++) {
                int row = n * 16 + l16;
                int cc  = kk * 4 + quad;
                int pc  = (row << 4) | (cc ^ (row & 7));
                short8 kf = *(const short8*)(&Kt[pc * 8]);
                sc[n] = __builtin_amdgcn_mfma_f32_16x16x32_bf16(qf[kk], kf, sc[n], 0, 0, 0);
            }
        }
        #pragma unroll
        for (int r = 0; r < 4; r++) {
            int   i_g = m0 + quad * 4 + r;
            int   jg0 = j0 + l16, jg1 = j0 + 16 + l16;
            bool  a0  = (jg0 <= i_g) && (i_g - jg0 < WIN);
            bool  a1  = (jg1 <= i_g) && (i_g - jg1 < WIN);
            float p0  = a0 ? exp2f(fmaf(sc[0][r], SC2, -FM)) : 0.f;
            float p1  = a1 ? exp2f(fmaf(sc[1][r], SC2, -FM)) : 0.f;
            l_part[r] += p0 + p1;
            int prow = w * 16 + quad * 4 + r;
            *(unsigned*)(&Pb[prow * 40 + 2 * l16]) = rne_pk(p0, p1);
        }
        {
            short8 pf = *(const short8*)(&Pb[(w * 16 + l16) * 40 + quad * 8]);
            #pragma unroll
            for (int nf = 0; nf < 8; nf++) {
                int dd = nf * 16 + l16;
                int qp = (dd << 2) | (quad ^ ((dd >> 2) & 3));
                short8 vf = *(const short8*)(&Vt[qp * 8]);
                acc[nf] = __builtin_amdgcn_mfma_f32_16x16x32_bf16(pf, vf, acc[nf], 0, 0, 0);
            }
        }
    }

    const float sk2 = exp2f(fmaf(sg[h], 1.4426950408889634f, -FM));
    float inv[4];
    #pragma unroll
    for (int r = 0; r < 4; r++) {
        float l = l_part[r];
        #pragma unroll
        for (int off = 1; off < 16; off <<= 1)
            l += __shfl_xor(l, off);
        inv[r] = 1.f / (l + sk2);
    }
    #pragma unroll
    for (int nf = 0; nf < 8; nf++) {
        int d = nf * 16 + l16;
        #pragma unroll
        for (int r = 0; r < 4; r++) {
            int ig = m0 + quad * 4 + r;
            outg[((size_t)ig * HQ + h) * DH + d] = acc[nf][r] * inv[r];
        }
    }
}

extern "C" void kernel_launch(void* const* d_in, const int* in_sizes, int n_in,
                              void* d_out, int out_size, void* d_ws, size_t ws_size,
                              hipStream_t stream) {
    const float* q  = (const float*)d_in[0];
    const float* k  = (const float*)d_in[1];
    const float* v  = (const float*)d_in[2];
    const float* sk = (const float*)d_in[3];
    float* out = (float*)d_out;

    const size_t tile_elems = (size_t)HKV * NT * TILE_CH * 8;   // u16 elems per tensor
    const size_t need = 2 * tile_elems * sizeof(u16);           // 8 MB

    if (ws_size >= need) {
        u16* kp  = (u16*)d_ws;
        u16* vtp = kp + tile_elems;
        pack_kv<<<dim3(HKV * NT), 256, 0, stream>>>(k, v, kp, vtp);
        fa_kernel<<<dim3((S_LEN / BR) * HQ), 256, 0, stream>>>(q, kp, vtp, sk, out);
    } else {
        fa_fallback<<<dim3((S_LEN / BR) * HQ), 256, 0, stream>>>(q, k, v, sk, out);
    }
}